// Round 5
// baseline (269.039 us; speedup 1.0000x reference)
//
#include <hip/hip_runtime.h>
#include <hip/hip_fp16.h>
#include <math.h>

constexpr int INDIM = 256;
constexpr int HID   = 128;
constexpr int HEADS = 4;
constexpr int HC    = HEADS * HID;   // 512

typedef __attribute__((ext_vector_type(8))) _Float16 f16x8;
typedef __attribute__((ext_vector_type(4))) float    f32x4;

#define GLOAD_LDS16(gsrc, ldst)                                                        \
  __builtin_amdgcn_global_load_lds((const __attribute__((address_space(1))) void*)(gsrc), \
                                   (__attribute__((address_space(3))) void*)(ldst), 16, 0, 0)

// ---------------- MFMA f16 GEMM, 128x64 tile, 4 waves (used for small-N GEMM) ----------
__global__ __launch_bounds__(256) void gemm_f16_mfma(const __half* __restrict__ A,
                                                     const __half* __restrict__ BT,
                                                     float* __restrict__ Cf,
                                                     __half* __restrict__ Ch,
                                                     const float* __restrict__ bias,
                                                     int M, int N, int K) {
  __shared__ _Float16 Asm[128 * 32];
  __shared__ _Float16 Bsm[64 * 32];
  const int tid = threadIdx.x;
  const int w = tid >> 6, l = tid & 63;
  const int wr = w >> 1, wc = w & 1;
  const int row0 = blockIdx.y * 128, col0 = blockIdx.x * 64;

  const int src_kq   = (l & 3) ^ ((l >> 2) & 3) ^ ((l >> 4) & 3);
  const int read_off = (((l >> 4) ^ (l & 3) ^ ((l >> 2) & 3)) * 8);

  f32x4 acc[4][2] = {};

  for (int kt = 0; kt < K; kt += 32) {
#pragma unroll
    for (int c = 0; c < 2; ++c) {
      const int R0 = w * 32 + c * 16;
      int row = row0 + R0 + (l >> 2);
      if (row >= M) row = M - 1;
      GLOAD_LDS16(&A[(size_t)row * K + kt + src_kq * 8], &Asm[R0 * 32]);
    }
    {
      const int R0 = w * 16;
      const int row = col0 + R0 + (l >> 2);
      GLOAD_LDS16(&BT[(size_t)row * K + kt + src_kq * 8], &Bsm[R0 * 32]);
    }
    __syncthreads();

    f16x8 bfr[2];
#pragma unroll
    for (int nf = 0; nf < 2; ++nf) {
      const int nl = wc * 32 + nf * 16 + (l & 15);
      bfr[nf] = *(const f16x8*)&Bsm[nl * 32 + read_off];
    }
#pragma unroll
    for (int mf = 0; mf < 4; ++mf) {
      const int ml = wr * 64 + mf * 16 + (l & 15);
      const f16x8 afr = *(const f16x8*)&Asm[ml * 32 + read_off];
#pragma unroll
      for (int nf = 0; nf < 2; ++nf)
        acc[mf][nf] = __builtin_amdgcn_mfma_f32_16x16x32_f16(afr, bfr[nf], acc[mf][nf], 0, 0, 0);
    }
    __syncthreads();
  }

#pragma unroll
  for (int mf = 0; mf < 4; ++mf) {
#pragma unroll
    for (int r = 0; r < 4; ++r) {
      const int row = row0 + wr * 64 + mf * 16 + (l >> 4) * 4 + r;
      if (row < M) {
#pragma unroll
        for (int nf = 0; nf < 2; ++nf) {
          const int col = col0 + wc * 32 + nf * 16 + (l & 15);
          const float v = acc[mf][nf][r];
          if (Ch) Ch[(size_t)row * N + col] = __float2half(v);
          else    Cf[(size_t)row * N + col] = v + (bias ? bias[col] : 0.f);
        }
      }
    }
  }
}

// ---------------- MFMA f16 GEMM, 128x128 tile, 8 waves (layer GEMMs, N%128==0) --------
__global__ __launch_bounds__(512) void gemm_f16_mfma_128(const __half* __restrict__ A,
                                                         const __half* __restrict__ BT,
                                                         __half* __restrict__ Ch,
                                                         int M, int N, int K) {
  __shared__ _Float16 Asm[128 * 32];   // 8 KB
  __shared__ _Float16 Bsm[128 * 32];   // 8 KB
  const int tid = threadIdx.x;
  const int w = tid >> 6, l = tid & 63;
  const int wr = w >> 2, wc = w & 3;          // 2 x 4 wave grid, each 64r x 32c
  const int row0 = blockIdx.y * 128, col0 = blockIdx.x * 128;

  const int src_kq   = (l & 3) ^ ((l >> 2) & 3) ^ ((l >> 4) & 3);
  const int read_off = (((l >> 4) ^ (l & 3) ^ ((l >> 2) & 3)) * 8);

  f32x4 acc[4][2] = {};

  for (int kt = 0; kt < K; kt += 32) {
    // one gload per thread per matrix: wave w stages rows [16w,16w+16)
    const int R0 = w * 16;
    int rowA = row0 + R0 + (l >> 2);
    if (rowA >= M) rowA = M - 1;
    GLOAD_LDS16(&A[(size_t)rowA * K + kt + src_kq * 8], &Asm[R0 * 32]);
    const int rowB = col0 + R0 + (l >> 2);
    GLOAD_LDS16(&BT[(size_t)rowB * K + kt + src_kq * 8], &Bsm[R0 * 32]);
    __syncthreads();

    f16x8 bfr[2];
#pragma unroll
    for (int nf = 0; nf < 2; ++nf) {
      const int nl = wc * 32 + nf * 16 + (l & 15);
      bfr[nf] = *(const f16x8*)&Bsm[nl * 32 + read_off];
    }
#pragma unroll
    for (int mf = 0; mf < 4; ++mf) {
      const int ml = wr * 64 + mf * 16 + (l & 15);
      const f16x8 afr = *(const f16x8*)&Asm[ml * 32 + read_off];
#pragma unroll
      for (int nf = 0; nf < 2; ++nf)
        acc[mf][nf] = __builtin_amdgcn_mfma_f32_16x16x32_f16(afr, bfr[nf], acc[mf][nf], 0, 0, 0);
    }
    __syncthreads();
  }

#pragma unroll
  for (int mf = 0; mf < 4; ++mf) {
#pragma unroll
    for (int r = 0; r < 4; ++r) {
      const int row = row0 + wr * 64 + mf * 16 + (l >> 4) * 4 + r;
      if (row < M) {
#pragma unroll
        for (int nf = 0; nf < 2; ++nf) {
          const int col = col0 + wc * 32 + nf * 16 + (l & 15);
          Ch[(size_t)row * N + col] = __float2half(acc[mf][nf][r]);
        }
      }
    }
  }
}

// ---------------- prep: f32 -> f16 convert / transpose ----------------
__global__ void cvt_f32_to_f16(const float* __restrict__ in, __half* __restrict__ out, int n) {
  const int i = (blockIdx.x * blockDim.x + threadIdx.x) * 4;
  if (i + 3 < n) {
    float4 v = *(const float4*)&in[i];
    __half2 a = __float22half2_rn(make_float2(v.x, v.y));
    __half2 b = __float22half2_rn(make_float2(v.z, v.w));
    *(uint2*)&out[i] = make_uint2(*(unsigned*)&a, *(unsigned*)&b);
  }
}

__global__ void transpose_to_f16(const float* __restrict__ W, __half* __restrict__ WT,
                                 int K, int N) {
  const int idx = blockIdx.x * blockDim.x + threadIdx.x;
  if (idx >= K * N) return;
  const int n = idx / K, k = idx % K;
  WT[idx] = __float2half(W[(size_t)k * N + n]);
}

// ---------------- per-node attention scores from fp16 features ----------------
__global__ __launch_bounds__(256) void scores_kernel(const __half* __restrict__ h,
                                                     const float* __restrict__ att_src,
                                                     const float* __restrict__ att_dst,
                                                     float* __restrict__ s_src,
                                                     float* __restrict__ s_dst) {
  const int n = blockIdx.x;
  const int wave = threadIdx.x >> 6;
  const int lane = threadIdx.x & 63;
  const float2 hv = __half22float2(*(const __half2*)&h[(size_t)n * HC + wave * HID + lane * 2]);
  const float2 as = *(const float2*)&att_src[wave * HID + lane * 2];
  const float2 ad = *(const float2*)&att_dst[wave * HID + lane * 2];
  float ss = hv.x * as.x + hv.y * as.y;
  float sd = hv.x * ad.x + hv.y * ad.y;
#pragma unroll
  for (int off = 32; off > 0; off >>= 1) {
    ss += __shfl_down(ss, off);
    sd += __shfl_down(sd, off);
  }
  if (lane == 0) {
    s_src[n * HEADS + wave] = ss;
    s_dst[n * HEADS + wave] = sd;
  }
}

// ---------------- CSR build (by dst) ----------------
__global__ void degree_kernel(const int* __restrict__ ei, int E, int N,
                              int* __restrict__ deg) {
  int e = blockIdx.x * blockDim.x + threadIdx.x;
  int total = E + N;
  if (e >= total) return;
  int dst = (e < E) ? ei[E + e] : (e - E);
  atomicAdd(&deg[dst], 1);
}

__global__ __launch_bounds__(1024) void scan_kernel(const int* __restrict__ deg,
                                                    int* __restrict__ rowstart,
                                                    int* __restrict__ cursor, int N) {
  __shared__ int sums[1024];
  const int tid = threadIdx.x;
  const int per = (N + 1023) / 1024;
  int begin = tid * per;
  int end = begin + per; if (end > N) end = N;
  if (begin > N) begin = N;
  int s = 0;
  for (int i = begin; i < end; ++i) s += deg[i];
  sums[tid] = s;
  __syncthreads();
  for (int off = 1; off < 1024; off <<= 1) {
    int v = (tid >= off) ? sums[tid - off] : 0;
    __syncthreads();
    sums[tid] += v;
    __syncthreads();
  }
  int run = (tid == 0) ? 0 : sums[tid - 1];
  for (int i = begin; i < end; ++i) {
    rowstart[i] = run;
    cursor[i] = run;
    run += deg[i];
  }
  if (tid == 1023) rowstart[N] = sums[1023];
}

__global__ void scatter_kernel(const int* __restrict__ ei, int E, int N,
                               int* __restrict__ cursor, int* __restrict__ csr_src) {
  int e = blockIdx.x * blockDim.x + threadIdx.x;
  int total = E + N;
  if (e >= total) return;
  int src, dst;
  if (e < E) { src = ei[e]; dst = ei[E + e]; }
  else       { src = dst = e - E; }
  int pos = atomicAdd(&cursor[dst], 1);
  csr_src[pos] = src;
}

// ---------------- fused segment-softmax + aggregate + head-mean + bias + elu ---------
// Phase 1: exact per-head max (edge-parallel over 64 lanes, shfl reduce).
// Phase 2: fixed-max weighted gather (no rescale; fma_mix on f16 operand).
// Phase 3: plain-sum merge across waves + head mean + bias + elu.
__global__ __launch_bounds__(256) void gat_aggregate(const __half* __restrict__ h,
                                                     const float* __restrict__ ssrc,
                                                     const float* __restrict__ sdst,
                                                     const int* __restrict__ rowstart,
                                                     const int* __restrict__ csr_src,
                                                     const float* __restrict__ bias,
                                                     __half* __restrict__ out,
                                                     int apply_elu) {
  const int n = blockIdx.x;
  const int wave = threadIdx.x >> 6;
  const int lane = threadIdx.x & 63;
  const int hsel = lane >> 4;
  const int sub  = lane & 15;
  const int rs = rowstart[n], re = rowstart[n + 1];
  const float sdh = sdst[n * HEADS + hsel];

  __shared__ float smax[4][4];     // [wave][head]
  __shared__ float sdn[4][64];
  __shared__ float sa[4][64][9];

  // ---- phase 1: exact max per head ----
  float mloc = -1e30f;
  for (int j = rs + wave * 16 + sub; j < re; j += 64) {
    const int s = csr_src[j];
    float e = ssrc[s * HEADS + hsel] + sdh;
    e = (e > 0.f) ? e : 0.2f * e;
    mloc = fmaxf(mloc, e);
  }
  mloc = fmaxf(mloc, __shfl_xor(mloc, 1));
  mloc = fmaxf(mloc, __shfl_xor(mloc, 2));
  mloc = fmaxf(mloc, __shfl_xor(mloc, 4));
  mloc = fmaxf(mloc, __shfl_xor(mloc, 8));
  if (sub == 0) smax[wave][hsel] = mloc;
  __syncthreads();
  const float M = fmaxf(fmaxf(smax[0][hsel], smax[1][hsel]),
                        fmaxf(smax[2][hsel], smax[3][hsel]));

  // ---- phase 2: weighted gather, fixed max ----
  float d = 0.f;
  float a[8] = {};
  for (int j = rs + wave; j < re; j += 8) {
    const int jB = j + 4;
    const float maskB = (jB < re) ? 1.f : 0.f;
    const int sA = csr_src[j];
    const int sB = csr_src[(jB < re) ? jB : j];
    float eA = ssrc[sA * HEADS + hsel] + sdh;
    float eB = ssrc[sB * HEADS + hsel] + sdh;
    eA = (eA > 0.f) ? eA : 0.2f * eA;
    eB = (eB > 0.f) ? eB : 0.2f * eB;
    const float wA = __expf(eA - M);
    const float wB = __expf(eB - M) * maskB;
    const int4 rawA = *(const int4*)&h[(size_t)sA * HC + lane * 8];
    const int4 rawB = *(const int4*)&h[(size_t)sB * HC + lane * 8];
    const __half* phA = (const __half*)&rawA;
    const __half* phB = (const __half*)&rawB;
    d += wA + wB;
#pragma unroll
    for (int k = 0; k < 8; ++k) {
      a[k] = fmaf(wA, __half2float(phA[k]), a[k]);
      a[k] = fmaf(wB, __half2float(phB[k]), a[k]);
    }
  }

  // ---- phase 3: merge (plain sums) ----
  sdn[wave][lane] = d;
#pragma unroll
  for (int k = 0; k < 8; ++k) sa[wave][lane][k] = a[k];
  __syncthreads();

  if (wave == 0) {
    float Dg = sdn[0][lane] + sdn[1][lane] + sdn[2][lane] + sdn[3][lane];
    float g[8];
#pragma unroll
    for (int k = 0; k < 8; ++k)
      g[k] = sa[0][lane][k] + sa[1][lane][k] + sa[2][lane][k] + sa[3][lane][k];
    const float inv = 1.f / (Dg + 1e-16f);
#pragma unroll
    for (int k = 0; k < 8; ++k) g[k] *= inv;
#pragma unroll
    for (int k = 0; k < 8; ++k) {
      g[k] += __shfl_xor(g[k], 16);
      g[k] += __shfl_xor(g[k], 32);
    }
    if (lane < 16) {
      const int c0 = lane * 8;
      __half hv[8];
#pragma unroll
      for (int k = 0; k < 8; ++k) {
        float t = 0.25f * g[k] + bias[c0 + k];
        if (apply_elu) t = (t > 0.f) ? t : expm1f(t);
        hv[k] = __float2half(t);
      }
      *(int4*)&out[(size_t)n * HID + c0] = *(int4*)hv;
    }
  }
}

// ---------------- launch ----------------
extern "C" void kernel_launch(void* const* d_in, const int* in_sizes, int n_in,
                              void* d_out, int out_size, void* d_ws, size_t ws_size,
                              hipStream_t stream) {
  const float* x    = (const float*)d_in[0];
  const int*   ei   = (const int*)d_in[1];
  const float* W1   = (const float*)d_in[2];
  const float* as1  = (const float*)d_in[3];
  const float* ad1  = (const float*)d_in[4];
  const float* b1   = (const float*)d_in[5];
  const float* W2   = (const float*)d_in[6];
  const float* as2  = (const float*)d_in[7];
  const float* ad2  = (const float*)d_in[8];
  const float* b2   = (const float*)d_in[9];
  const float* Wout = (const float*)d_in[10];
  const float* bout = (const float*)d_in[11];
  float* out = (float*)d_out;

  const int N = in_sizes[0] / INDIM;   // 20000
  const int E = in_sizes[1] / 2;       // 320000
  const int total = E + N;

  char* p = (char*)d_ws;
  auto alloc = [&](size_t bytes) -> void* {
    void* r = (void*)p;
    p += (bytes + 255) & ~(size_t)255;
    return r;
  };
  __half* x16  = (__half*)alloc((size_t)N * INDIM * 2);
  __half* h16  = (__half*)alloc((size_t)N * HC * 2);
  __half* t1h  = (__half*)alloc((size_t)N * HID * 2);
  __half* t2h  = (__half*)alloc((size_t)N * HID * 2);
  __half* w1t  = (__half*)alloc((size_t)INDIM * HC * 2);
  __half* w2t  = (__half*)alloc((size_t)HID * HC * 2);
  __half* wot  = (__half*)alloc((size_t)HID * HID * 2);
  float* ssrc  = (float*)alloc((size_t)N * HEADS * 4);
  float* sdst  = (float*)alloc((size_t)N * HEADS * 4);
  int* deg     = (int*)alloc((size_t)N * 4);
  int* rowst   = (int*)alloc(((size_t)N + 1) * 4);
  int* cursor  = (int*)alloc((size_t)N * 4);
  int* csr     = (int*)alloc((size_t)total * 4);

  cvt_f32_to_f16<<<(N * INDIM / 4 + 255) / 256, 256, 0, stream>>>(x, x16, N * INDIM);
  transpose_to_f16<<<(INDIM * HC + 255) / 256, 256, 0, stream>>>(W1, w1t, INDIM, HC);
  transpose_to_f16<<<(HID * HC + 255) / 256, 256, 0, stream>>>(W2, w2t, HID, HC);
  transpose_to_f16<<<(HID * HID + 255) / 256, 256, 0, stream>>>(Wout, wot, HID, HID);

  hipMemsetAsync(deg, 0, (size_t)N * 4, stream);
  degree_kernel<<<(total + 255) / 256, 256, 0, stream>>>(ei, E, N, deg);
  scan_kernel<<<1, 1024, 0, stream>>>(deg, rowst, cursor, N);
  scatter_kernel<<<(total + 255) / 256, 256, 0, stream>>>(ei, E, N, cursor, csr);

  const int mblk = (N + 127) / 128;
  // layer 1: h = x @ W1   [20000,256]x[256,512]
  gemm_f16_mfma_128<<<dim3(HC / 128, mblk), 512, 0, stream>>>(x16, w1t, h16, N, HC, INDIM);
  scores_kernel<<<N, 256, 0, stream>>>(h16, as1, ad1, ssrc, sdst);
  gat_aggregate<<<N, 256, 0, stream>>>(h16, ssrc, sdst, rowst, csr, b1, t1h, 1);
  // layer 2: h = t1 @ W2  [20000,128]x[128,512]
  gemm_f16_mfma_128<<<dim3(HC / 128, mblk), 512, 0, stream>>>(t1h, w2t, h16, N, HC, HID);
  scores_kernel<<<N, 256, 0, stream>>>(h16, as2, ad2, ssrc, sdst);
  gat_aggregate<<<N, 256, 0, stream>>>(h16, ssrc, sdst, rowst, csr, b2, t2h, 1);
  // output projection: out = t2 @ W_out + bout  [20000,128]x[128,128], f32 out
  gemm_f16_mfma<<<dim3(HID / 64, mblk), 256, 0, stream>>>(t2h, wot, out, nullptr, bout, N, HID, HID);
}

// Round 6
// 254.135 us; speedup vs baseline: 1.0586x; 1.0586x over previous
//
#include <hip/hip_runtime.h>
#include <hip/hip_fp16.h>
#include <math.h>

constexpr int INDIM = 256;
constexpr int HID   = 128;
constexpr int HEADS = 4;
constexpr int HC    = HEADS * HID;   // 512

typedef __attribute__((ext_vector_type(8))) _Float16 f16x8;
typedef __attribute__((ext_vector_type(4))) float    f32x4;

#define GLOAD_LDS16(gsrc, ldst)                                                        \
  __builtin_amdgcn_global_load_lds((const __attribute__((address_space(1))) void*)(gsrc), \
                                   (__attribute__((address_space(3))) void*)(ldst), 16, 0, 0)

// ---------------- MFMA f16 GEMM, 128x64 tile, 4 waves (small-N GEMM) ----------------
__global__ __launch_bounds__(256) void gemm_f16_mfma(const __half* __restrict__ A,
                                                     const __half* __restrict__ BT,
                                                     float* __restrict__ Cf,
                                                     __half* __restrict__ Ch,
                                                     const float* __restrict__ bias,
                                                     int M, int N, int K) {
  __shared__ _Float16 Asm[128 * 32];
  __shared__ _Float16 Bsm[64 * 32];
  const int tid = threadIdx.x;
  const int w = tid >> 6, l = tid & 63;
  const int wr = w >> 1, wc = w & 1;
  const int row0 = blockIdx.y * 128, col0 = blockIdx.x * 64;

  const int src_kq   = (l & 3) ^ ((l >> 2) & 3) ^ ((l >> 4) & 3);
  const int read_off = (((l >> 4) ^ (l & 3) ^ ((l >> 2) & 3)) * 8);

  f32x4 acc[4][2] = {};

  for (int kt = 0; kt < K; kt += 32) {
#pragma unroll
    for (int c = 0; c < 2; ++c) {
      const int R0 = w * 32 + c * 16;
      int row = row0 + R0 + (l >> 2);
      if (row >= M) row = M - 1;
      GLOAD_LDS16(&A[(size_t)row * K + kt + src_kq * 8], &Asm[R0 * 32]);
    }
    {
      const int R0 = w * 16;
      const int row = col0 + R0 + (l >> 2);
      GLOAD_LDS16(&BT[(size_t)row * K + kt + src_kq * 8], &Bsm[R0 * 32]);
    }
    __syncthreads();

    f16x8 bfr[2];
#pragma unroll
    for (int nf = 0; nf < 2; ++nf) {
      const int nl = wc * 32 + nf * 16 + (l & 15);
      bfr[nf] = *(const f16x8*)&Bsm[nl * 32 + read_off];
    }
#pragma unroll
    for (int mf = 0; mf < 4; ++mf) {
      const int ml = wr * 64 + mf * 16 + (l & 15);
      const f16x8 afr = *(const f16x8*)&Asm[ml * 32 + read_off];
#pragma unroll
      for (int nf = 0; nf < 2; ++nf)
        acc[mf][nf] = __builtin_amdgcn_mfma_f32_16x16x32_f16(afr, bfr[nf], acc[mf][nf], 0, 0, 0);
    }
    __syncthreads();
  }

#pragma unroll
  for (int mf = 0; mf < 4; ++mf) {
#pragma unroll
    for (int r = 0; r < 4; ++r) {
      const int row = row0 + wr * 64 + mf * 16 + (l >> 4) * 4 + r;
      if (row < M) {
#pragma unroll
        for (int nf = 0; nf < 2; ++nf) {
          const int col = col0 + wc * 32 + nf * 16 + (l & 15);
          const float v = acc[mf][nf][r];
          if (Ch) Ch[(size_t)row * N + col] = __float2half(v);
          else    Cf[(size_t)row * N + col] = v + (bias ? bias[col] : 0.f);
        }
      }
    }
  }
}

// ---------------- MFMA f16 GEMM, 128x128 tile, 8 waves (layer GEMMs) ----------------
__global__ __launch_bounds__(512) void gemm_f16_mfma_128(const __half* __restrict__ A,
                                                         const __half* __restrict__ BT,
                                                         __half* __restrict__ Ch,
                                                         int M, int N, int K) {
  __shared__ _Float16 Asm[128 * 32];
  __shared__ _Float16 Bsm[128 * 32];
  const int tid = threadIdx.x;
  const int w = tid >> 6, l = tid & 63;
  const int wr = w >> 2, wc = w & 3;
  const int row0 = blockIdx.y * 128, col0 = blockIdx.x * 128;

  const int src_kq   = (l & 3) ^ ((l >> 2) & 3) ^ ((l >> 4) & 3);
  const int read_off = (((l >> 4) ^ (l & 3) ^ ((l >> 2) & 3)) * 8);

  f32x4 acc[4][2] = {};

  for (int kt = 0; kt < K; kt += 32) {
    const int R0 = w * 16;
    int rowA = row0 + R0 + (l >> 2);
    if (rowA >= M) rowA = M - 1;
    GLOAD_LDS16(&A[(size_t)rowA * K + kt + src_kq * 8], &Asm[R0 * 32]);
    const int rowB = col0 + R0 + (l >> 2);
    GLOAD_LDS16(&BT[(size_t)rowB * K + kt + src_kq * 8], &Bsm[R0 * 32]);
    __syncthreads();

    f16x8 bfr[2];
#pragma unroll
    for (int nf = 0; nf < 2; ++nf) {
      const int nl = wc * 32 + nf * 16 + (l & 15);
      bfr[nf] = *(const f16x8*)&Bsm[nl * 32 + read_off];
    }
#pragma unroll
    for (int mf = 0; mf < 4; ++mf) {
      const int ml = wr * 64 + mf * 16 + (l & 15);
      const f16x8 afr = *(const f16x8*)&Asm[ml * 32 + read_off];
#pragma unroll
      for (int nf = 0; nf < 2; ++nf)
        acc[mf][nf] = __builtin_amdgcn_mfma_f32_16x16x32_f16(afr, bfr[nf], acc[mf][nf], 0, 0, 0);
    }
    __syncthreads();
  }

#pragma unroll
  for (int mf = 0; mf < 4; ++mf) {
#pragma unroll
    for (int r = 0; r < 4; ++r) {
      const int row = row0 + wr * 64 + mf * 16 + (l >> 4) * 4 + r;
      if (row < M) {
#pragma unroll
        for (int nf = 0; nf < 2; ++nf) {
          const int col = col0 + wc * 32 + nf * 16 + (l & 15);
          Ch[(size_t)row * N + col] = __float2half(acc[mf][nf][r]);
        }
      }
    }
  }
}

// ---------------- prep: f32 -> f16 convert / transpose ----------------
__global__ void cvt_f32_to_f16(const float* __restrict__ in, __half* __restrict__ out, int n) {
  const int i = (blockIdx.x * blockDim.x + threadIdx.x) * 4;
  if (i + 3 < n) {
    float4 v = *(const float4*)&in[i];
    __half2 a = __float22half2_rn(make_float2(v.x, v.y));
    __half2 b = __float22half2_rn(make_float2(v.z, v.w));
    *(uint2*)&out[i] = make_uint2(*(unsigned*)&a, *(unsigned*)&b);
  }
}

__global__ void transpose_to_f16(const float* __restrict__ W, __half* __restrict__ WT,
                                 int K, int N) {
  const int idx = blockIdx.x * blockDim.x + threadIdx.x;
  if (idx >= K * N) return;
  const int n = idx / K, k = idx % K;
  WT[idx] = __float2half(W[(size_t)k * N + n]);
}

// ---------------- per-node attention scores from fp16 features ----------------
__global__ __launch_bounds__(256) void scores_kernel(const __half* __restrict__ h,
                                                     const float* __restrict__ att_src,
                                                     const float* __restrict__ att_dst,
                                                     float* __restrict__ s_src,
                                                     float* __restrict__ s_dst) {
  const int n = blockIdx.x;
  const int wave = threadIdx.x >> 6;
  const int lane = threadIdx.x & 63;
  const float2 hv = __half22float2(*(const __half2*)&h[(size_t)n * HC + wave * HID + lane * 2]);
  const float2 as = *(const float2*)&att_src[wave * HID + lane * 2];
  const float2 ad = *(const float2*)&att_dst[wave * HID + lane * 2];
  float ss = hv.x * as.x + hv.y * as.y;
  float sd = hv.x * ad.x + hv.y * ad.y;
#pragma unroll
  for (int off = 32; off > 0; off >>= 1) {
    ss += __shfl_down(ss, off);
    sd += __shfl_down(sd, off);
  }
  if (lane == 0) {
    s_src[n * HEADS + wave] = ss;
    s_dst[n * HEADS + wave] = sd;
  }
}

// ---------------- CSR build (by dst) ----------------
__global__ void degree_kernel(const int* __restrict__ ei, int E, int N,
                              int* __restrict__ deg) {
  int e = blockIdx.x * blockDim.x + threadIdx.x;
  int total = E + N;
  if (e >= total) return;
  int dst = (e < E) ? ei[E + e] : (e - E);
  atomicAdd(&deg[dst], 1);
}

__global__ __launch_bounds__(1024) void scan_kernel(const int* __restrict__ deg,
                                                    int* __restrict__ rowstart,
                                                    int* __restrict__ cursor, int N) {
  __shared__ int sums[1024];
  const int tid = threadIdx.x;
  const int per = (N + 1023) / 1024;
  int begin = tid * per;
  int end = begin + per; if (end > N) end = N;
  if (begin > N) begin = N;
  int s = 0;
  for (int i = begin; i < end; ++i) s += deg[i];
  sums[tid] = s;
  __syncthreads();
  for (int off = 1; off < 1024; off <<= 1) {
    int v = (tid >= off) ? sums[tid - off] : 0;
    __syncthreads();
    sums[tid] += v;
    __syncthreads();
  }
  int run = (tid == 0) ? 0 : sums[tid - 1];
  for (int i = begin; i < end; ++i) {
    rowstart[i] = run;
    cursor[i] = run;
    run += deg[i];
  }
  if (tid == 1023) rowstart[N] = sums[1023];
}

__global__ void scatter_kernel(const int* __restrict__ ei, int E, int N,
                               int* __restrict__ cursor, int* __restrict__ csr_src) {
  int e = blockIdx.x * blockDim.x + threadIdx.x;
  int total = E + N;
  if (e >= total) return;
  int src, dst;
  if (e < E) { src = ei[e]; dst = ei[E + e]; }
  else       { src = dst = e - E; }
  int pos = atomicAdd(&cursor[dst], 1);
  csr_src[pos] = src;
}

// ---------------- fused segment-softmax + aggregate + head-mean + bias + elu ---------
// Max-free softmax (shift-invariant; scores ~N(0,2), clamp 60 is a no-op guard
// against overflow: exp(60)*deg*|h| << f32 max). Single pass, dual independent
// chains per wave for load concurrency, plain-sum merge across waves.
__global__ __launch_bounds__(256) void gat_aggregate(const __half* __restrict__ h,
                                                     const float* __restrict__ ssrc,
                                                     const float* __restrict__ sdst,
                                                     const int* __restrict__ rowstart,
                                                     const int* __restrict__ csr_src,
                                                     const float* __restrict__ bias,
                                                     __half* __restrict__ out,
                                                     int apply_elu) {
  const int n = blockIdx.x;
  const int wave = threadIdx.x >> 6;
  const int lane = threadIdx.x & 63;
  const int hsel = lane >> 4;
  const int rs = rowstart[n], re = rowstart[n + 1];
  const float sdh = sdst[n * HEADS + hsel];

  float d = 0.f;
  float a[8] = {};
  for (int j = rs + wave; j < re; j += 8) {
    const int jB = j + 4;
    const float maskB = (jB < re) ? 1.f : 0.f;
    const int sA = csr_src[j];
    const int sB = csr_src[(jB < re) ? jB : j];
    float eA = ssrc[sA * HEADS + hsel] + sdh;
    float eB = ssrc[sB * HEADS + hsel] + sdh;
    eA = (eA > 0.f) ? eA : 0.2f * eA;
    eB = (eB > 0.f) ? eB : 0.2f * eB;
    const float wA = __expf(fminf(eA, 60.f));
    const float wB = __expf(fminf(eB, 60.f)) * maskB;
    const int4 rawA = *(const int4*)&h[(size_t)sA * HC + lane * 8];
    const int4 rawB = *(const int4*)&h[(size_t)sB * HC + lane * 8];
    const __half* phA = (const __half*)&rawA;
    const __half* phB = (const __half*)&rawB;
    d += wA + wB;
#pragma unroll
    for (int k = 0; k < 8; ++k) {
      a[k] = fmaf(wA, __half2float(phA[k]), a[k]);
      a[k] = fmaf(wB, __half2float(phB[k]), a[k]);
    }
  }

  // merge across waves (plain sums)
  __shared__ float sdn[4][64];
  __shared__ float sa[4][64][9];
  sdn[wave][lane] = d;
#pragma unroll
  for (int k = 0; k < 8; ++k) sa[wave][lane][k] = a[k];
  __syncthreads();

  if (wave == 0) {
    float Dg = sdn[0][lane] + sdn[1][lane] + sdn[2][lane] + sdn[3][lane];
    float g[8];
#pragma unroll
    for (int k = 0; k < 8; ++k)
      g[k] = sa[0][lane][k] + sa[1][lane][k] + sa[2][lane][k] + sa[3][lane][k];
    const float inv = 1.f / (Dg + 1e-16f);
#pragma unroll
    for (int k = 0; k < 8; ++k) g[k] *= inv;
#pragma unroll
    for (int k = 0; k < 8; ++k) {
      g[k] += __shfl_xor(g[k], 16);
      g[k] += __shfl_xor(g[k], 32);
    }
    if (lane < 16) {
      const int c0 = lane * 8;
      __half hv[8];
#pragma unroll
      for (int k = 0; k < 8; ++k) {
        float t = 0.25f * g[k] + bias[c0 + k];
        if (apply_elu) t = (t > 0.f) ? t : expm1f(t);
        hv[k] = __float2half(t);
      }
      *(int4*)&out[(size_t)n * HID + c0] = *(int4*)hv;
    }
  }
}

// ---------------- launch ----------------
extern "C" void kernel_launch(void* const* d_in, const int* in_sizes, int n_in,
                              void* d_out, int out_size, void* d_ws, size_t ws_size,
                              hipStream_t stream) {
  const float* x    = (const float*)d_in[0];
  const int*   ei   = (const int*)d_in[1];
  const float* W1   = (const float*)d_in[2];
  const float* as1  = (const float*)d_in[3];
  const float* ad1  = (const float*)d_in[4];
  const float* b1   = (const float*)d_in[5];
  const float* W2   = (const float*)d_in[6];
  const float* as2  = (const float*)d_in[7];
  const float* ad2  = (const float*)d_in[8];
  const float* b2   = (const float*)d_in[9];
  const float* Wout = (const float*)d_in[10];
  const float* bout = (const float*)d_in[11];
  float* out = (float*)d_out;

  const int N = in_sizes[0] / INDIM;   // 20000
  const int E = in_sizes[1] / 2;       // 320000
  const int total = E + N;

  char* p = (char*)d_ws;
  auto alloc = [&](size_t bytes) -> void* {
    void* r = (void*)p;
    p += (bytes + 255) & ~(size_t)255;
    return r;
  };
  __half* x16  = (__half*)alloc((size_t)N * INDIM * 2);
  __half* h16  = (__half*)alloc((size_t)N * HC * 2);
  __half* t1h  = (__half*)alloc((size_t)N * HID * 2);
  __half* t2h  = (__half*)alloc((size_t)N * HID * 2);
  __half* w1t  = (__half*)alloc((size_t)INDIM * HC * 2);
  __half* w2t  = (__half*)alloc((size_t)HID * HC * 2);
  __half* wot  = (__half*)alloc((size_t)HID * HID * 2);
  float* ssrc  = (float*)alloc((size_t)N * HEADS * 4);
  float* sdst  = (float*)alloc((size_t)N * HEADS * 4);
  int* deg     = (int*)alloc((size_t)N * 4);
  int* rowst   = (int*)alloc(((size_t)N + 1) * 4);
  int* cursor  = (int*)alloc((size_t)N * 4);
  int* csr     = (int*)alloc((size_t)total * 4);

  cvt_f32_to_f16<<<(N * INDIM / 4 + 255) / 256, 256, 0, stream>>>(x, x16, N * INDIM);
  transpose_to_f16<<<(INDIM * HC + 255) / 256, 256, 0, stream>>>(W1, w1t, INDIM, HC);
  transpose_to_f16<<<(HID * HC + 255) / 256, 256, 0, stream>>>(W2, w2t, HID, HC);
  transpose_to_f16<<<(HID * HID + 255) / 256, 256, 0, stream>>>(Wout, wot, HID, HID);

  hipMemsetAsync(deg, 0, (size_t)N * 4, stream);
  degree_kernel<<<(total + 255) / 256, 256, 0, stream>>>(ei, E, N, deg);
  scan_kernel<<<1, 1024, 0, stream>>>(deg, rowst, cursor, N);
  scatter_kernel<<<(total + 255) / 256, 256, 0, stream>>>(ei, E, N, cursor, csr);

  const int mblk = (N + 127) / 128;
  // layer 1: h = x @ W1   [20000,256]x[256,512]
  gemm_f16_mfma_128<<<dim3(HC / 128, mblk), 512, 0, stream>>>(x16, w1t, h16, N, HC, INDIM);
  scores_kernel<<<N, 256, 0, stream>>>(h16, as1, ad1, ssrc, sdst);
  gat_aggregate<<<N, 256, 0, stream>>>(h16, ssrc, sdst, rowst, csr, b1, t1h, 1);
  // layer 2: h = t1 @ W2  [20000,128]x[128,512]
  gemm_f16_mfma_128<<<dim3(HC / 128, mblk), 512, 0, stream>>>(t1h, w2t, h16, N, HC, HID);
  scores_kernel<<<N, 256, 0, stream>>>(h16, as2, ad2, ssrc, sdst);
  gat_aggregate<<<N, 256, 0, stream>>>(h16, ssrc, sdst, rowst, csr, b2, t2h, 1);
  // output projection: out = t2 @ W_out + bout  [20000,128]x[128,128], f32 out
  gemm_f16_mfma<<<dim3(HID / 64, mblk), 256, 0, stream>>>(t2h, wot, out, nullptr, bout, N, HID, HID);
}

// Round 7
// 238.916 us; speedup vs baseline: 1.1261x; 1.0637x over previous
//
#include <hip/hip_runtime.h>
#include <hip/hip_fp16.h>
#include <math.h>

constexpr int INDIM = 256;
constexpr int HID   = 128;
constexpr int HEADS = 4;
constexpr int HC    = HEADS * HID;   // 512

typedef __attribute__((ext_vector_type(8))) _Float16 f16x8;
typedef __attribute__((ext_vector_type(4))) float    f32x4;

#define GLOAD_LDS16(gsrc, ldst)                                                        \
  __builtin_amdgcn_global_load_lds((const __attribute__((address_space(1))) void*)(gsrc), \
                                   (__attribute__((address_space(3))) void*)(ldst), 16, 0, 0)

// ---------------- MFMA f16 GEMM, 128x64 tile, 4 waves (final projection) ----------------
__global__ __launch_bounds__(256) void gemm_f16_mfma(const __half* __restrict__ A,
                                                     const __half* __restrict__ BT,
                                                     float* __restrict__ Cf,
                                                     const float* __restrict__ bias,
                                                     int M, int N, int K) {
  __shared__ _Float16 Asm[128 * 32];
  __shared__ _Float16 Bsm[64 * 32];
  const int tid = threadIdx.x;
  const int w = tid >> 6, l = tid & 63;
  const int wr = w >> 1, wc = w & 1;
  const int row0 = blockIdx.y * 128, col0 = blockIdx.x * 64;

  const int src_kq   = (l & 3) ^ ((l >> 2) & 3) ^ ((l >> 4) & 3);
  const int read_off = (((l >> 4) ^ (l & 3) ^ ((l >> 2) & 3)) * 8);

  f32x4 acc[4][2] = {};

  for (int kt = 0; kt < K; kt += 32) {
#pragma unroll
    for (int c = 0; c < 2; ++c) {
      const int R0 = w * 32 + c * 16;
      int row = row0 + R0 + (l >> 2);
      if (row >= M) row = M - 1;
      GLOAD_LDS16(&A[(size_t)row * K + kt + src_kq * 8], &Asm[R0 * 32]);
    }
    {
      const int R0 = w * 16;
      const int row = col0 + R0 + (l >> 2);
      GLOAD_LDS16(&BT[(size_t)row * K + kt + src_kq * 8], &Bsm[R0 * 32]);
    }
    __syncthreads();

    f16x8 bfr[2];
#pragma unroll
    for (int nf = 0; nf < 2; ++nf) {
      const int nl = wc * 32 + nf * 16 + (l & 15);
      bfr[nf] = *(const f16x8*)&Bsm[nl * 32 + read_off];
    }
#pragma unroll
    for (int mf = 0; mf < 4; ++mf) {
      const int ml = wr * 64 + mf * 16 + (l & 15);
      const f16x8 afr = *(const f16x8*)&Asm[ml * 32 + read_off];
#pragma unroll
      for (int nf = 0; nf < 2; ++nf)
        acc[mf][nf] = __builtin_amdgcn_mfma_f32_16x16x32_f16(afr, bfr[nf], acc[mf][nf], 0, 0, 0);
    }
    __syncthreads();
  }

#pragma unroll
  for (int mf = 0; mf < 4; ++mf) {
#pragma unroll
    for (int r = 0; r < 4; ++r) {
      const int row = row0 + wr * 64 + mf * 16 + (l >> 4) * 4 + r;
      if (row < M) {
#pragma unroll
        for (int nf = 0; nf < 2; ++nf) {
          const int col = col0 + wc * 32 + nf * 16 + (l & 15);
          Cf[(size_t)row * N + col] = acc[mf][nf][r] + bias[col];
        }
      }
    }
  }
}

// ---------------- MFMA f16 GEMM, 128x128 tile, 8 waves (layer GEMMs) ----------------
// When att_src != null: each 128-col block == one head; epilogue computes
// s_src[row,head], s_dst[row,head] exactly from the f32 accumulators.
__global__ __launch_bounds__(512) void gemm_f16_mfma_128(const __half* __restrict__ A,
                                                         const __half* __restrict__ BT,
                                                         __half* __restrict__ Ch,
                                                         const float* __restrict__ att_src,
                                                         const float* __restrict__ att_dst,
                                                         float* __restrict__ ssrc,
                                                         float* __restrict__ sdst,
                                                         int M, int N, int K) {
  __shared__ _Float16 Asm[128 * 32];
  __shared__ _Float16 Bsm[128 * 32];
  const int tid = threadIdx.x;
  const int w = tid >> 6, l = tid & 63;
  const int wr = w >> 2, wc = w & 3;
  const int row0 = blockIdx.y * 128, col0 = blockIdx.x * 128;

  const int src_kq   = (l & 3) ^ ((l >> 2) & 3) ^ ((l >> 4) & 3);
  const int read_off = (((l >> 4) ^ (l & 3) ^ ((l >> 2) & 3)) * 8);

  f32x4 acc[4][2] = {};

  for (int kt = 0; kt < K; kt += 32) {
    const int R0 = w * 16;
    int rowA = row0 + R0 + (l >> 2);
    if (rowA >= M) rowA = M - 1;
    GLOAD_LDS16(&A[(size_t)rowA * K + kt + src_kq * 8], &Asm[R0 * 32]);
    const int rowB = col0 + R0 + (l >> 2);
    GLOAD_LDS16(&BT[(size_t)rowB * K + kt + src_kq * 8], &Bsm[R0 * 32]);
    __syncthreads();

    f16x8 bfr[2];
#pragma unroll
    for (int nf = 0; nf < 2; ++nf) {
      const int nl = wc * 32 + nf * 16 + (l & 15);
      bfr[nf] = *(const f16x8*)&Bsm[nl * 32 + read_off];
    }
#pragma unroll
    for (int mf = 0; mf < 4; ++mf) {
      const int ml = wr * 64 + mf * 16 + (l & 15);
      const f16x8 afr = *(const f16x8*)&Asm[ml * 32 + read_off];
#pragma unroll
      for (int nf = 0; nf < 2; ++nf)
        acc[mf][nf] = __builtin_amdgcn_mfma_f32_16x16x32_f16(afr, bfr[nf], acc[mf][nf], 0, 0, 0);
    }
    __syncthreads();
  }

#pragma unroll
  for (int mf = 0; mf < 4; ++mf) {
#pragma unroll
    for (int r = 0; r < 4; ++r) {
      const int row = row0 + wr * 64 + mf * 16 + (l >> 4) * 4 + r;
      if (row < M) {
#pragma unroll
        for (int nf = 0; nf < 2; ++nf) {
          const int col = col0 + wc * 32 + nf * 16 + (l & 15);
          Ch[(size_t)row * N + col] = __float2half(acc[mf][nf][r]);
        }
      }
    }
  }

  // fused attention-score epilogue (head == col-block)
  if (att_src) {
    const int head = col0 / HID;
    float asv[2], adv[2];
#pragma unroll
    for (int nf = 0; nf < 2; ++nf) {
      const int c = wc * 32 + nf * 16 + (l & 15);
      asv[nf] = att_src[head * HID + c];
      adv[nf] = att_dst[head * HID + c];
    }
    __shared__ float sred[2][128][4];
#pragma unroll
    for (int mf = 0; mf < 4; ++mf) {
#pragma unroll
      for (int r = 0; r < 4; ++r) {
        float ps = acc[mf][0][r] * asv[0] + acc[mf][1][r] * asv[1];
        float pd = acc[mf][0][r] * adv[0] + acc[mf][1][r] * adv[1];
#pragma unroll
        for (int mk = 1; mk < 16; mk <<= 1) {
          ps += __shfl_xor(ps, mk);
          pd += __shfl_xor(pd, mk);
        }
        if ((l & 15) == 0) {
          const int rl = wr * 64 + mf * 16 + (l >> 4) * 4 + r;
          sred[0][rl][wc] = ps;
          sred[1][rl][wc] = pd;
        }
      }
    }
    __syncthreads();
    if (tid < 128) {
      const int row = row0 + tid;
      if (row < M) {
        ssrc[row * HEADS + head] = sred[0][tid][0] + sred[0][tid][1] + sred[0][tid][2] + sred[0][tid][3];
        sdst[row * HEADS + head] = sred[1][tid][0] + sred[1][tid][1] + sred[1][tid][2] + sred[1][tid][3];
      }
    }
  }
}

// ---------------- fused prep: x->f16 + all weight transposes ----------------
__global__ void prep_fused(const float* __restrict__ x, __half* __restrict__ x16, int nx4,
                           const float* __restrict__ W1, __half* __restrict__ w1t,
                           const float* __restrict__ W2, __half* __restrict__ w2t,
                           const float* __restrict__ Wo, __half* __restrict__ wot) {
  int g = blockIdx.x * blockDim.x + threadIdx.x;
  if (g < nx4) {
    const int i = g * 4;
    float4 v = *(const float4*)&x[i];
    __half2 a = __float22half2_rn(make_float2(v.x, v.y));
    __half2 b = __float22half2_rn(make_float2(v.z, v.w));
    *(uint2*)&x16[i] = make_uint2(*(unsigned*)&a, *(unsigned*)&b);
    return;
  }
  g -= nx4;
  if (g < INDIM * HC) {                 // w1t[n*256+k] = W1[k*512+n]
    const int n = g / INDIM, k = g % INDIM;
    w1t[g] = __float2half(W1[(size_t)k * HC + n]);
    return;
  }
  g -= INDIM * HC;
  if (g < HID * HC) {                   // w2t[n*128+k] = W2[k*512+n]
    const int n = g / HID, k = g % HID;
    w2t[g] = __float2half(W2[(size_t)k * HC + n]);
    return;
  }
  g -= HID * HC;
  if (g < HID * HID) {                  // wot[n*128+k] = Wo[k*128+n]
    const int n = g / HID, k = g % HID;
    wot[g] = __float2half(Wo[(size_t)k * HID + n]);
  }
}

// ---------------- CSR build (by dst) ----------------
__global__ void degree_kernel(const int* __restrict__ ei, int E, int N,
                              int* __restrict__ deg) {
  int e = blockIdx.x * blockDim.x + threadIdx.x;
  int total = E + N;
  if (e >= total) return;
  int dst = (e < E) ? ei[E + e] : (e - E);
  atomicAdd(&deg[dst], 1);
}

__global__ __launch_bounds__(1024) void scan_kernel(const int* __restrict__ deg,
                                                    int* __restrict__ rowstart,
                                                    int* __restrict__ cursor, int N) {
  __shared__ int sums[1024];
  const int tid = threadIdx.x;
  const int per = (N + 1023) / 1024;
  int begin = tid * per;
  int end = begin + per; if (end > N) end = N;
  if (begin > N) begin = N;
  int s = 0;
  for (int i = begin; i < end; ++i) s += deg[i];
  sums[tid] = s;
  __syncthreads();
  for (int off = 1; off < 1024; off <<= 1) {
    int v = (tid >= off) ? sums[tid - off] : 0;
    __syncthreads();
    sums[tid] += v;
    __syncthreads();
  }
  int run = (tid == 0) ? 0 : sums[tid - 1];
  for (int i = begin; i < end; ++i) {
    rowstart[i] = run;
    cursor[i] = run;
    run += deg[i];
  }
  if (tid == 1023) rowstart[N] = sums[1023];
}

__global__ void scatter_kernel(const int* __restrict__ ei, int E, int N,
                               int* __restrict__ cursor,
                               int* __restrict__ csr_src, int* __restrict__ csr_dst) {
  int e = blockIdx.x * blockDim.x + threadIdx.x;
  int total = E + N;
  if (e >= total) return;
  int src, dst;
  if (e < E) { src = ei[e]; dst = ei[E + e]; }
  else       { src = dst = e - E; }
  int pos = atomicAdd(&cursor[dst], 1);
  csr_src[pos] = src;
  csr_dst[pos] = dst;
}

// ---------------- per-edge softmax weights (CSR order) ----------------
// wtab[j][h] = exp(min(leaky(ssrc[src,h]+sdst[dst,h]), 60)). Score tables are
// L2-resident (320 KB each); output write fully coalesced.
__global__ void edge_weights(const int* __restrict__ csr_src,
                             const int* __restrict__ csr_dst,
                             const float4* __restrict__ ssrc4,
                             const float4* __restrict__ sdst4,
                             float4* __restrict__ wtab, int total) {
  const int j = blockIdx.x * blockDim.x + threadIdx.x;
  if (j >= total) return;
  const float4 s = ssrc4[csr_src[j]];
  const float4 dq = sdst4[csr_dst[j]];
  float e0 = s.x + dq.x, e1 = s.y + dq.y, e2 = s.z + dq.z, e3 = s.w + dq.w;
  e0 = (e0 > 0.f) ? e0 : 0.2f * e0;
  e1 = (e1 > 0.f) ? e1 : 0.2f * e1;
  e2 = (e2 > 0.f) ? e2 : 0.2f * e2;
  e3 = (e3 > 0.f) ? e3 : 0.2f * e3;
  float4 wv;
  wv.x = __expf(fminf(e0, 60.f));
  wv.y = __expf(fminf(e1, 60.f));
  wv.z = __expf(fminf(e2, 60.f));
  wv.w = __expf(fminf(e3, 60.f));
  wtab[j] = wv;
}

// ---------------- fused aggregate + head-mean + bias + elu ----------------
// Gather loop with precomputed weights: wtab load (indexed by j, independent)
// + h load (csr_src prefetched one iteration ahead) -> ~1 dependent round-trip
// per iteration. Dual chains x 4 waves, plain-sum merge.
__global__ __launch_bounds__(256) void gat_aggregate(const __half* __restrict__ h,
                                                     const float* __restrict__ wtab,
                                                     const int* __restrict__ rowstart,
                                                     const int* __restrict__ csr_src,
                                                     const float* __restrict__ bias,
                                                     __half* __restrict__ out,
                                                     int apply_elu) {
  const int n = blockIdx.x;
  const int wave = threadIdx.x >> 6;
  const int lane = threadIdx.x & 63;
  const int hsel = lane >> 4;
  const int rs = rowstart[n], re = rowstart[n + 1];

  float d = 0.f;
  float a[8] = {};
  int j = rs + wave;
  int sA = csr_src[(j < re) ? j : rs];
  int sB = csr_src[(j + 4 < re) ? j + 4 : rs];
  for (; j < re; j += 8) {
    const int jB = j + 4;
    const int jn = j + 8, jnB = j + 12;
    const int nsA = csr_src[(jn  < re) ? jn  : rs];
    const int nsB = csr_src[(jnB < re) ? jnB : rs];
    const float wA = wtab[j * 4 + hsel];
    const float wB = (jB < re) ? wtab[jB * 4 + hsel] : 0.f;
    const int4 rawA = *(const int4*)&h[(size_t)sA * HC + lane * 8];
    const int4 rawB = *(const int4*)&h[(size_t)sB * HC + lane * 8];
    const __half* phA = (const __half*)&rawA;
    const __half* phB = (const __half*)&rawB;
    d += wA + wB;
#pragma unroll
    for (int k = 0; k < 8; ++k) {
      a[k] = fmaf(wA, __half2float(phA[k]), a[k]);
      a[k] = fmaf(wB, __half2float(phB[k]), a[k]);
    }
    sA = nsA; sB = nsB;
  }

  // merge across waves (plain sums)
  __shared__ float sdn[4][64];
  __shared__ float sa[4][64][9];
  sdn[wave][lane] = d;
#pragma unroll
  for (int k = 0; k < 8; ++k) sa[wave][lane][k] = a[k];
  __syncthreads();

  if (wave == 0) {
    float Dg = sdn[0][lane] + sdn[1][lane] + sdn[2][lane] + sdn[3][lane];
    float g[8];
#pragma unroll
    for (int k = 0; k < 8; ++k)
      g[k] = sa[0][lane][k] + sa[1][lane][k] + sa[2][lane][k] + sa[3][lane][k];
    const float inv = 1.f / (Dg + 1e-16f);
#pragma unroll
    for (int k = 0; k < 8; ++k) g[k] *= inv;
#pragma unroll
    for (int k = 0; k < 8; ++k) {
      g[k] += __shfl_xor(g[k], 16);
      g[k] += __shfl_xor(g[k], 32);
    }
    if (lane < 16) {
      const int c0 = lane * 8;
      __half hv[8];
#pragma unroll
      for (int k = 0; k < 8; ++k) {
        float t = 0.25f * g[k] + bias[c0 + k];
        if (apply_elu) t = (t > 0.f) ? t : expm1f(t);
        hv[k] = __float2half(t);
      }
      *(int4*)&out[(size_t)n * HID + c0] = *(int4*)hv;
    }
  }
}

// ---------------- launch ----------------
extern "C" void kernel_launch(void* const* d_in, const int* in_sizes, int n_in,
                              void* d_out, int out_size, void* d_ws, size_t ws_size,
                              hipStream_t stream) {
  const float* x    = (const float*)d_in[0];
  const int*   ei   = (const int*)d_in[1];
  const float* W1   = (const float*)d_in[2];
  const float* as1  = (const float*)d_in[3];
  const float* ad1  = (const float*)d_in[4];
  const float* b1   = (const float*)d_in[5];
  const float* W2   = (const float*)d_in[6];
  const float* as2  = (const float*)d_in[7];
  const float* ad2  = (const float*)d_in[8];
  const float* b2   = (const float*)d_in[9];
  const float* Wout = (const float*)d_in[10];
  const float* bout = (const float*)d_in[11];
  float* out = (float*)d_out;

  const int N = in_sizes[0] / INDIM;   // 20000
  const int E = in_sizes[1] / 2;       // 320000
  const int total = E + N;

  char* p = (char*)d_ws;
  auto alloc = [&](size_t bytes) -> void* {
    void* r = (void*)p;
    p += (bytes + 255) & ~(size_t)255;
    return r;
  };
  __half* x16  = (__half*)alloc((size_t)N * INDIM * 2);
  __half* h16  = (__half*)alloc((size_t)N * HC * 2);
  __half* t1h  = (__half*)alloc((size_t)N * HID * 2);
  __half* t2h  = (__half*)alloc((size_t)N * HID * 2);
  __half* w1t  = (__half*)alloc((size_t)INDIM * HC * 2);
  __half* w2t  = (__half*)alloc((size_t)HID * HC * 2);
  __half* wot  = (__half*)alloc((size_t)HID * HID * 2);
  float* ssrc  = (float*)alloc((size_t)N * HEADS * 4);
  float* sdst  = (float*)alloc((size_t)N * HEADS * 4);
  float* wtab  = (float*)alloc((size_t)total * HEADS * 4);
  int* deg     = (int*)alloc((size_t)N * 4);
  int* rowst   = (int*)alloc(((size_t)N + 1) * 4);
  int* cursor  = (int*)alloc((size_t)N * 4);
  int* csr_s   = (int*)alloc((size_t)total * 4);
  int* csr_d   = (int*)alloc((size_t)total * 4);

  // fused prep
  const int nx4 = N * INDIM / 4;
  const int prep_total = nx4 + INDIM * HC + HID * HC + HID * HID;
  prep_fused<<<(prep_total + 255) / 256, 256, 0, stream>>>(x, x16, nx4, W1, w1t, W2, w2t, Wout, wot);

  // CSR build
  hipMemsetAsync(deg, 0, (size_t)N * 4, stream);
  degree_kernel<<<(total + 255) / 256, 256, 0, stream>>>(ei, E, N, deg);
  scan_kernel<<<1, 1024, 0, stream>>>(deg, rowst, cursor, N);
  scatter_kernel<<<(total + 255) / 256, 256, 0, stream>>>(ei, E, N, cursor, csr_s, csr_d);

  const int mblk = (N + 127) / 128;
  const int eblk = (total + 255) / 256;
  // layer 1
  gemm_f16_mfma_128<<<dim3(HC / 128, mblk), 512, 0, stream>>>(x16, w1t, h16, as1, ad1, ssrc, sdst, N, HC, INDIM);
  edge_weights<<<eblk, 256, 0, stream>>>(csr_s, csr_d, (const float4*)ssrc, (const float4*)sdst, (float4*)wtab, total);
  gat_aggregate<<<N, 256, 0, stream>>>(h16, wtab, rowst, csr_s, b1, t1h, 1);
  // layer 2
  gemm_f16_mfma_128<<<dim3(HC / 128, mblk), 512, 0, stream>>>(t1h, w2t, h16, as2, ad2, ssrc, sdst, N, HC, HID);
  edge_weights<<<eblk, 256, 0, stream>>>(csr_s, csr_d, (const float4*)ssrc, (const float4*)sdst, (float4*)wtab, total);
  gat_aggregate<<<N, 256, 0, stream>>>(h16, wtab, rowst, csr_s, b2, t2h, 1);
  // output projection
  gemm_f16_mfma<<<dim3(HID / 64, mblk), 256, 0, stream>>>(t2h, wot, out, bout, N, HID, HID);
}

// Round 8
// 215.740 us; speedup vs baseline: 1.2470x; 1.1074x over previous
//
#include <hip/hip_runtime.h>
#include <hip/hip_fp16.h>
#include <math.h>

constexpr int INDIM = 256;
constexpr int HID   = 128;
constexpr int HEADS = 4;
constexpr int HC    = HEADS * HID;   // 512

typedef __attribute__((ext_vector_type(8))) _Float16 f16x8;
typedef __attribute__((ext_vector_type(4))) float    f32x4;

#define GLOAD_LDS16(gsrc, ldst)                                                        \
  __builtin_amdgcn_global_load_lds((const __attribute__((address_space(1))) void*)(gsrc), \
                                   (__attribute__((address_space(3))) void*)(ldst), 16, 0, 0)

// ---------------- MFMA f16 GEMM, 128x64 tile, 4 waves (final projection) ----------------
__global__ __launch_bounds__(256) void gemm_f16_mfma(const __half* __restrict__ A,
                                                     const __half* __restrict__ BT,
                                                     float* __restrict__ Cf,
                                                     const float* __restrict__ bias,
                                                     int M, int N, int K) {
  __shared__ _Float16 Asm[128 * 32];
  __shared__ _Float16 Bsm[64 * 32];
  const int tid = threadIdx.x;
  const int w = tid >> 6, l = tid & 63;
  const int wr = w >> 1, wc = w & 1;
  const int row0 = blockIdx.y * 128, col0 = blockIdx.x * 64;

  const int src_kq   = (l & 3) ^ ((l >> 2) & 3) ^ ((l >> 4) & 3);
  const int read_off = (((l >> 4) ^ (l & 3) ^ ((l >> 2) & 3)) * 8);

  f32x4 acc[4][2] = {};

  for (int kt = 0; kt < K; kt += 32) {
#pragma unroll
    for (int c = 0; c < 2; ++c) {
      const int R0 = w * 32 + c * 16;
      int row = row0 + R0 + (l >> 2);
      if (row >= M) row = M - 1;
      GLOAD_LDS16(&A[(size_t)row * K + kt + src_kq * 8], &Asm[R0 * 32]);
    }
    {
      const int R0 = w * 16;
      const int row = col0 + R0 + (l >> 2);
      GLOAD_LDS16(&BT[(size_t)row * K + kt + src_kq * 8], &Bsm[R0 * 32]);
    }
    __syncthreads();

    f16x8 bfr[2];
#pragma unroll
    for (int nf = 0; nf < 2; ++nf) {
      const int nl = wc * 32 + nf * 16 + (l & 15);
      bfr[nf] = *(const f16x8*)&Bsm[nl * 32 + read_off];
    }
#pragma unroll
    for (int mf = 0; mf < 4; ++mf) {
      const int ml = wr * 64 + mf * 16 + (l & 15);
      const f16x8 afr = *(const f16x8*)&Asm[ml * 32 + read_off];
#pragma unroll
      for (int nf = 0; nf < 2; ++nf)
        acc[mf][nf] = __builtin_amdgcn_mfma_f32_16x16x32_f16(afr, bfr[nf], acc[mf][nf], 0, 0, 0);
    }
    __syncthreads();
  }

#pragma unroll
  for (int mf = 0; mf < 4; ++mf) {
#pragma unroll
    for (int r = 0; r < 4; ++r) {
      const int row = row0 + wr * 64 + mf * 16 + (l >> 4) * 4 + r;
      if (row < M) {
#pragma unroll
        for (int nf = 0; nf < 2; ++nf) {
          const int col = col0 + wc * 32 + nf * 16 + (l & 15);
          Cf[(size_t)row * N + col] = acc[mf][nf][r] + bias[col];
        }
      }
    }
  }
}

// ---------------- MFMA f16 GEMM, 128x128 tile, 8 waves (layer GEMMs) ----------------
// att_src != null: 128-col block == one head; epilogue emits exact s_src/s_dst.
__global__ __launch_bounds__(512) void gemm_f16_mfma_128(const __half* __restrict__ A,
                                                         const __half* __restrict__ BT,
                                                         __half* __restrict__ Ch,
                                                         const float* __restrict__ att_src,
                                                         const float* __restrict__ att_dst,
                                                         float* __restrict__ ssrc,
                                                         float* __restrict__ sdst,
                                                         int M, int N, int K) {
  __shared__ _Float16 Asm[128 * 32];
  __shared__ _Float16 Bsm[128 * 32];
  const int tid = threadIdx.x;
  const int w = tid >> 6, l = tid & 63;
  const int wr = w >> 2, wc = w & 3;
  const int row0 = blockIdx.y * 128, col0 = blockIdx.x * 128;

  const int src_kq   = (l & 3) ^ ((l >> 2) & 3) ^ ((l >> 4) & 3);
  const int read_off = (((l >> 4) ^ (l & 3) ^ ((l >> 2) & 3)) * 8);

  f32x4 acc[4][2] = {};

  for (int kt = 0; kt < K; kt += 32) {
    const int R0 = w * 16;
    int rowA = row0 + R0 + (l >> 2);
    if (rowA >= M) rowA = M - 1;
    GLOAD_LDS16(&A[(size_t)rowA * K + kt + src_kq * 8], &Asm[R0 * 32]);
    const int rowB = col0 + R0 + (l >> 2);
    GLOAD_LDS16(&BT[(size_t)rowB * K + kt + src_kq * 8], &Bsm[R0 * 32]);
    __syncthreads();

    f16x8 bfr[2];
#pragma unroll
    for (int nf = 0; nf < 2; ++nf) {
      const int nl = wc * 32 + nf * 16 + (l & 15);
      bfr[nf] = *(const f16x8*)&Bsm[nl * 32 + read_off];
    }
#pragma unroll
    for (int mf = 0; mf < 4; ++mf) {
      const int ml = wr * 64 + mf * 16 + (l & 15);
      const f16x8 afr = *(const f16x8*)&Asm[ml * 32 + read_off];
#pragma unroll
      for (int nf = 0; nf < 2; ++nf)
        acc[mf][nf] = __builtin_amdgcn_mfma_f32_16x16x32_f16(afr, bfr[nf], acc[mf][nf], 0, 0, 0);
    }
    __syncthreads();
  }

#pragma unroll
  for (int mf = 0; mf < 4; ++mf) {
#pragma unroll
    for (int r = 0; r < 4; ++r) {
      const int row = row0 + wr * 64 + mf * 16 + (l >> 4) * 4 + r;
      if (row < M) {
#pragma unroll
        for (int nf = 0; nf < 2; ++nf) {
          const int col = col0 + wc * 32 + nf * 16 + (l & 15);
          Ch[(size_t)row * N + col] = __float2half(acc[mf][nf][r]);
        }
      }
    }
  }

  if (att_src) {
    const int head = col0 / HID;
    float asv[2], adv[2];
#pragma unroll
    for (int nf = 0; nf < 2; ++nf) {
      const int c = wc * 32 + nf * 16 + (l & 15);
      asv[nf] = att_src[head * HID + c];
      adv[nf] = att_dst[head * HID + c];
    }
    __shared__ float sred[2][128][4];
#pragma unroll
    for (int mf = 0; mf < 4; ++mf) {
#pragma unroll
      for (int r = 0; r < 4; ++r) {
        float ps = acc[mf][0][r] * asv[0] + acc[mf][1][r] * asv[1];
        float pd = acc[mf][0][r] * adv[0] + acc[mf][1][r] * adv[1];
#pragma unroll
        for (int mk = 1; mk < 16; mk <<= 1) {
          ps += __shfl_xor(ps, mk);
          pd += __shfl_xor(pd, mk);
        }
        if ((l & 15) == 0) {
          const int rl = wr * 64 + mf * 16 + (l >> 4) * 4 + r;
          sred[0][rl][wc] = ps;
          sred[1][rl][wc] = pd;
        }
      }
    }
    __syncthreads();
    if (tid < 128) {
      const int row = row0 + tid;
      if (row < M) {
        ssrc[row * HEADS + head] = sred[0][tid][0] + sred[0][tid][1] + sred[0][tid][2] + sred[0][tid][3];
        sdst[row * HEADS + head] = sred[1][tid][0] + sred[1][tid][1] + sred[1][tid][2] + sred[1][tid][3];
      }
    }
  }
}

// ---------------- fused prep: x->f16 + all weight transposes ----------------
__global__ void prep_fused(const float* __restrict__ x, __half* __restrict__ x16, int nx4,
                           const float* __restrict__ W1, __half* __restrict__ w1t,
                           const float* __restrict__ W2, __half* __restrict__ w2t,
                           const float* __restrict__ Wo, __half* __restrict__ wot) {
  int g = blockIdx.x * blockDim.x + threadIdx.x;
  if (g < nx4) {
    const int i = g * 4;
    float4 v = *(const float4*)&x[i];
    __half2 a = __float22half2_rn(make_float2(v.x, v.y));
    __half2 b = __float22half2_rn(make_float2(v.z, v.w));
    *(uint2*)&x16[i] = make_uint2(*(unsigned*)&a, *(unsigned*)&b);
    return;
  }
  g -= nx4;
  if (g < INDIM * HC) {
    const int n = g / INDIM, k = g % INDIM;
    w1t[g] = __float2half(W1[(size_t)k * HC + n]);
    return;
  }
  g -= INDIM * HC;
  if (g < HID * HC) {
    const int n = g / HID, k = g % HID;
    w2t[g] = __float2half(W2[(size_t)k * HC + n]);
    return;
  }
  g -= HID * HC;
  if (g < HID * HID) {
    const int n = g / HID, k = g % HID;
    wot[g] = __float2half(Wo[(size_t)k * HID + n]);
  }
}

// ---------------- CSR build (by dst) ----------------
__global__ void degree_kernel(const int* __restrict__ ei, int E, int N,
                              int* __restrict__ deg) {
  int e = blockIdx.x * blockDim.x + threadIdx.x;
  int total = E + N;
  if (e >= total) return;
  int dst = (e < E) ? ei[E + e] : (e - E);
  atomicAdd(&deg[dst], 1);
}

// int4-vectorized single-block scan (N multiple of 4; per-thread span multiple of 4)
__global__ __launch_bounds__(1024) void scan_kernel(const int* __restrict__ deg,
                                                    int* __restrict__ rowstart,
                                                    int* __restrict__ cursor, int N) {
  __shared__ int sums[1024];
  const int tid = threadIdx.x;
  const int per = ((N + 1023) / 1024 + 3) & ~3;
  int begin = tid * per;
  int end = begin + per; if (end > N) end = N;
  if (begin > N) begin = N;
  int s = 0;
  for (int i = begin; i + 3 < end; i += 4) {
    int4 v = *(const int4*)&deg[i];
    s += v.x + v.y + v.z + v.w;
  }
  sums[tid] = s;
  __syncthreads();
  for (int off = 1; off < 1024; off <<= 1) {
    int v = (tid >= off) ? sums[tid - off] : 0;
    __syncthreads();
    sums[tid] += v;
    __syncthreads();
  }
  int run = (tid == 0) ? 0 : sums[tid - 1];
  for (int i = begin; i + 3 < end; i += 4) {
    int4 v = *(const int4*)&deg[i];
    int4 rr;
    rr.x = run;
    rr.y = run + v.x;
    rr.z = run + v.x + v.y;
    rr.w = run + v.x + v.y + v.z;
    *(int4*)&rowstart[i] = rr;
    *(int4*)&cursor[i]   = rr;
    run += v.x + v.y + v.z + v.w;
  }
  if (tid == 1023) rowstart[N] = sums[1023];
}

// csr_boff holds PRE-SCALED byte offsets (src * HC * 2) for the h16 gather.
__global__ void scatter_kernel(const int* __restrict__ ei, int E, int N,
                               int* __restrict__ cursor,
                               int* __restrict__ csr_boff, int* __restrict__ csr_dst) {
  int e = blockIdx.x * blockDim.x + threadIdx.x;
  int total = E + N;
  if (e >= total) return;
  int src, dst;
  if (e < E) { src = ei[e]; dst = ei[E + e]; }
  else       { src = dst = e - E; }
  int pos = atomicAdd(&cursor[dst], 1);
  csr_boff[pos] = src * (HC * 2);
  csr_dst[pos] = dst;
}

// ---------------- per-edge softmax weights (CSR order) ----------------
__global__ void edge_weights(const int* __restrict__ csr_boff,
                             const int* __restrict__ csr_dst,
                             const float4* __restrict__ ssrc4,
                             const float4* __restrict__ sdst4,
                             float4* __restrict__ wtab, int total) {
  const int j = blockIdx.x * blockDim.x + threadIdx.x;
  if (j >= total) return;
  const float4 s = ssrc4[csr_boff[j] >> 10];
  const float4 dq = sdst4[csr_dst[j]];
  float e0 = s.x + dq.x, e1 = s.y + dq.y, e2 = s.z + dq.z, e3 = s.w + dq.w;
  e0 = (e0 > 0.f) ? e0 : 0.2f * e0;
  e1 = (e1 > 0.f) ? e1 : 0.2f * e1;
  e2 = (e2 > 0.f) ? e2 : 0.2f * e2;
  e3 = (e3 > 0.f) ? e3 : 0.2f * e3;
  float4 wv;
  wv.x = __expf(fminf(e0, 60.f));
  wv.y = __expf(fminf(e1, 60.f));
  wv.z = __expf(fminf(e2, 60.f));
  wv.w = __expf(fminf(e3, 60.f));
  wtab[j] = wv;
}

// ---------------- fused aggregate + head-mean + bias + elu ----------------
// Pre-scaled byte-offset gather: base + 32-bit offset + lane*16 (no per-edge
// 64-bit mul). Dual chains x 4 waves, precomputed weights, plain-sum merge.
__global__ __launch_bounds__(256) void gat_aggregate(const __half* __restrict__ h,
                                                     const float* __restrict__ wtab,
                                                     const int* __restrict__ rowstart,
                                                     const int* __restrict__ csr_boff,
                                                     const float* __restrict__ bias,
                                                     __half* __restrict__ out,
                                                     int apply_elu) {
  const int n = blockIdx.x;
  const int wave = threadIdx.x >> 6;
  const int lane = threadIdx.x & 63;
  const int hsel = lane >> 4;
  const int rs = rowstart[n], re = rowstart[n + 1];
  const char* hb = (const char*)h + lane * 16;

  float d = 0.f;
  float a[8] = {};
  int j = rs + wave;
  int oA = csr_boff[(j < re) ? j : rs];
  int oB = csr_boff[(j + 4 < re) ? j + 4 : rs];
  for (; j < re; j += 8) {
    const int jB = j + 4;
    const int jn = j + 8, jnB = j + 12;
    const int noA = csr_boff[(jn  < re) ? jn  : rs];
    const int noB = csr_boff[(jnB < re) ? jnB : rs];
    const float wA = wtab[j * 4 + hsel];
    const float wB = (jB < re) ? wtab[jB * 4 + hsel] : 0.f;
    const int4 rawA = *(const int4*)(hb + oA);
    const int4 rawB = *(const int4*)(hb + oB);
    const __half* phA = (const __half*)&rawA;
    const __half* phB = (const __half*)&rawB;
    d += wA + wB;
#pragma unroll
    for (int k = 0; k < 8; ++k) {
      a[k] = fmaf(wA, __half2float(phA[k]), a[k]);
      a[k] = fmaf(wB, __half2float(phB[k]), a[k]);
    }
    oA = noA; oB = noB;
  }

  __shared__ float sdn[4][64];
  __shared__ float sa[4][64][9];
  sdn[wave][lane] = d;
#pragma unroll
  for (int k = 0; k < 8; ++k) sa[wave][lane][k] = a[k];
  __syncthreads();

  if (wave == 0) {
    float Dg = sdn[0][lane] + sdn[1][lane] + sdn[2][lane] + sdn[3][lane];
    float g[8];
#pragma unroll
    for (int k = 0; k < 8; ++k)
      g[k] = sa[0][lane][k] + sa[1][lane][k] + sa[2][lane][k] + sa[3][lane][k];
    const float inv = 1.f / (Dg + 1e-16f);
#pragma unroll
    for (int k = 0; k < 8; ++k) g[k] *= inv;
#pragma unroll
    for (int k = 0; k < 8; ++k) {
      g[k] += __shfl_xor(g[k], 16);
      g[k] += __shfl_xor(g[k], 32);
    }
    if (lane < 16) {
      const int c0 = lane * 8;
      __half hv[8];
#pragma unroll
      for (int k = 0; k < 8; ++k) {
        float t = 0.25f * g[k] + bias[c0 + k];
        if (apply_elu) t = (t > 0.f) ? t : expm1f(t);
        hv[k] = __float2half(t);
      }
      *(int4*)&out[(size_t)n * HID + c0] = *(int4*)hv;
    }
  }
}

// ---------------- launch ----------------
extern "C" void kernel_launch(void* const* d_in, const int* in_sizes, int n_in,
                              void* d_out, int out_size, void* d_ws, size_t ws_size,
                              hipStream_t stream) {
  const float* x    = (const float*)d_in[0];
  const int*   ei   = (const int*)d_in[1];
  const float* W1   = (const float*)d_in[2];
  const float* as1  = (const float*)d_in[3];
  const float* ad1  = (const float*)d_in[4];
  const float* b1   = (const float*)d_in[5];
  const float* W2   = (const float*)d_in[6];
  const float* as2  = (const float*)d_in[7];
  const float* ad2  = (const float*)d_in[8];
  const float* b2   = (const float*)d_in[9];
  const float* Wout = (const float*)d_in[10];
  const float* bout = (const float*)d_in[11];
  float* out = (float*)d_out;

  const int N = in_sizes[0] / INDIM;   // 20000
  const int E = in_sizes[1] / 2;       // 320000
  const int total = E + N;

  char* p = (char*)d_ws;
  auto alloc = [&](size_t bytes) -> void* {
    void* r = (void*)p;
    p += (bytes + 255) & ~(size_t)255;
    return r;
  };
  __half* x16  = (__half*)alloc((size_t)N * INDIM * 2);
  __half* h16  = (__half*)alloc((size_t)N * HC * 2);
  __half* t1h  = (__half*)alloc((size_t)N * HID * 2);
  __half* t2h  = (__half*)alloc((size_t)N * HID * 2);
  __half* w1t  = (__half*)alloc((size_t)INDIM * HC * 2);
  __half* w2t  = (__half*)alloc((size_t)HID * HC * 2);
  __half* wot  = (__half*)alloc((size_t)HID * HID * 2);
  float* ssrc  = (float*)alloc((size_t)N * HEADS * 4);
  float* sdst  = (float*)alloc((size_t)N * HEADS * 4);
  float* wtab  = (float*)alloc((size_t)total * HEADS * 4);
  int* deg     = (int*)alloc((size_t)N * 4);
  int* rowst   = (int*)alloc(((size_t)N + 4) * 4);
  int* cursor  = (int*)alloc((size_t)N * 4);
  int* csr_b   = (int*)alloc((size_t)total * 4);
  int* csr_d   = (int*)alloc((size_t)total * 4);

  const int nx4 = N * INDIM / 4;
  const int prep_total = nx4 + INDIM * HC + HID * HC + HID * HID;
  prep_fused<<<(prep_total + 255) / 256, 256, 0, stream>>>(x, x16, nx4, W1, w1t, W2, w2t, Wout, wot);

  hipMemsetAsync(deg, 0, (size_t)N * 4, stream);
  degree_kernel<<<(total + 255) / 256, 256, 0, stream>>>(ei, E, N, deg);
  scan_kernel<<<1, 1024, 0, stream>>>(deg, rowst, cursor, N);
  scatter_kernel<<<(total + 255) / 256, 256, 0, stream>>>(ei, E, N, cursor, csr_b, csr_d);

  const int mblk = (N + 127) / 128;
  const int eblk = (total + 255) / 256;
  // layer 1
  gemm_f16_mfma_128<<<dim3(HC / 128, mblk), 512, 0, stream>>>(x16, w1t, h16, as1, ad1, ssrc, sdst, N, HC, INDIM);
  edge_weights<<<eblk, 256, 0, stream>>>(csr_b, csr_d, (const float4*)ssrc, (const float4*)sdst, (float4*)wtab, total);
  gat_aggregate<<<N, 256, 0, stream>>>(h16, wtab, rowst, csr_b, b1, t1h, 1);
  // layer 2
  gemm_f16_mfma_128<<<dim3(HC / 128, mblk), 512, 0, stream>>>(t1h, w2t, h16, as2, ad2, ssrc, sdst, N, HC, HID);
  edge_weights<<<eblk, 256, 0, stream>>>(csr_b, csr_d, (const float4*)ssrc, (const float4*)sdst, (float4*)wtab, total);
  gat_aggregate<<<N, 256, 0, stream>>>(h16, wtab, rowst, csr_b, b2, t2h, 1);
  // output projection
  gemm_f16_mfma<<<dim3(HID / 64, mblk), 256, 0, stream>>>(t2h, wot, out, bout, N, HID, HID);
}